// Round 1
// 379.253 us; speedup vs baseline: 1.0024x; 1.0024x over previous
//
#include <hip/hip_runtime.h>
#include <hip/hip_bf16.h>
#include <stdint.h>

#define BATCH 8
#define SEQ   2048
#define EMB   256
#define ADIM  256

typedef __bf16 bf16_t;
typedef __attribute__((ext_vector_type(8))) __bf16 bf16x8;
typedef __attribute__((ext_vector_type(4))) float  f32x4;
typedef uint32_t u32;

static __device__ __forceinline__ f32x4 mfma16(bf16x8 a, bf16x8 b, f32x4 c) {
    return __builtin_amdgcn_mfma_f32_16x16x32_bf16(a, b, c, 0, 0, 0);
}

// async global->LDS DMA: lds dest = wave-uniform base + lane*16
static __device__ __forceinline__ void gld16(const void* g, void* l) {
    __builtin_amdgcn_global_load_lds((const __attribute__((address_space(1))) u32*)g,
                                     (__attribute__((address_space(3))) u32*)l, 16, 0, 0);
}

// ---------------- kernel 0: W^T (k,v) cast to bf16 -> d_out scratch ----------------
// wt[m][a][e] = (bf16) W_m[e][a]. d_out is dead for flash output until the memset;
// only proj (stream-ordered before the memset) reads wt. Proven rounds 2/5/7.
__global__ __launch_bounds__(256) void wtkv_kernel(const float* __restrict__ Wk,
                                                   const float* __restrict__ Wv,
                                                   bf16_t* __restrict__ wt) {
    int tid = blockIdx.x * 256 + threadIdx.x;   // 0 .. 2*65536-1
    int m = tid >> 16;
    int i = tid & 65535;
    int a = i >> 8, e = i & 255;
    const float* W = (m == 0) ? Wk : Wv;
    wt[m * 65536 + a * 256 + e] = (bf16_t)W[e * 256 + a];
}

// ---------------- kernel 1: fused K+V projection, coalesced stores ----------------
// One block = one 32-row kv tile; wave handles 16 rows and computes BOTH K and V
// (x rows loaded once -> halves x HBM traffic). Outputs are repacked through
// wave-private LDS so every global store is a coalesced dwordx4; this replaces
// the previous version's 8.4M scattered 2-byte stores (the inferred ~160us cost).
// Byte layouts of Ksw/Vsw are IDENTICAL to before (flash untouched):
//   Ksw: per batch 64 tiles x 16384 B; byte = n*512 + ((cb^(n&7))*16) + j*2
//        (n = s&31 kv row, cb = a>>3, j = a&7)
//   Vsw: byte = a*64 + (((k>>3) ^ (a&3) ^ ((a>>2)&3))*16) + (k&7)*2, k = s&31
// No barriers: LDS is wave-private; per-wave LDS ops retire in order (same
// pattern as flash's proven Pt repack).
__global__ __launch_bounds__(128, 1) void proj_kv(const float* __restrict__ x,
                                                  const bf16_t* __restrict__ wt,  // in d_out
                                                  const float* __restrict__ bk,
                                                  const float* __restrict__ bv,
                                                  char* __restrict__ Ksw,
                                                  char* __restrict__ Vsw) {
    __shared__ __align__(16) char stg[2][10240];   // per-wave repack buffer
    const int tid  = threadIdx.x;
    const int wid  = tid >> 6;
    const int lane = tid & 63;
    const int lq   = lane >> 4;
    const int ln   = lane & 15;
    const int blk  = blockIdx.x;                   // 0..511: one 32-row tile
    const int b    = blk >> 6;                     // batch
    const int tile = blk & 63;                     // tile within batch
    const int mbase = blk * 32 + wid * 16;         // this wave's 16 global rows
    char* S = stg[wid];

    // x fragments: this wave's 16 rows, full EMB (A-operand layout, round-4 proven)
    bf16x8 xf[8];
    const float* xp = x + (size_t)(mbase + ln) * EMB;
    #pragma unroll
    for (int c = 0; c < 8; ++c) {
        f32x4 a0 = *(const f32x4*)(xp + c * 32 + lq * 8);
        f32x4 a1 = *(const f32x4*)(xp + c * 32 + lq * 8 + 4);
        bf16x8 v;
        v[0] = (bf16_t)a0[0]; v[1] = (bf16_t)a0[1]; v[2] = (bf16_t)a0[2]; v[3] = (bf16_t)a0[3];
        v[4] = (bf16_t)a1[0]; v[5] = (bf16_t)a1[1]; v[6] = (bf16_t)a1[2]; v[7] = (bf16_t)a1[3];
        xf[c] = v;
    }

    f32x4 acc[16];

    // ======== K projection ========
    #pragma unroll
    for (int t = 0; t < 16; ++t) acc[t] = (f32x4){0.f, 0.f, 0.f, 0.f};
    {
        const bf16_t* w = wt;                      // K panel wt[0][a][e]
        #pragma unroll
        for (int c = 0; c < 8; ++c)
            #pragma unroll
            for (int t = 0; t < 16; ++t) {
                bf16x8 wf = *(const bf16x8*)(w + (size_t)(t * 16 + ln) * 256 + c * 32 + lq * 8);
                acc[t] = mfma16(xf[c], wf, acc[t]);
            }
    }
    // stage natural [row16][a256] bf16 (bias folded; identical rounding to before)
    #pragma unroll
    for (int t = 0; t < 16; ++t) {
        float bb = bk[t * 16 + ln];
        #pragma unroll
        for (int r = 0; r < 4; ++r)
            *(bf16_t*)(S + (lq * 4 + r) * 512 + (t * 16 + ln) * 2) = (bf16_t)(acc[t][r] + bb);
    }
    asm volatile("s_waitcnt lgkmcnt(0)" ::: "memory");
    // read with swizzle-on-index, store 1024B-contiguous per instruction
    {
        char* Kg = Ksw + (size_t)b * 1048576 + (size_t)tile * 16384 + wid * 8192;
        const int rh = lane >> 5;                  // which of the 2 rows this pass
        const int p  = lane & 31;                  // chunk position within 512B row
        #pragma unroll
        for (int i = 0; i < 8; ++i) {
            int row = i * 2 + rh;                  // local row 0..15
            int n   = wid * 16 + row;              // kv row within tile
            int cb  = p ^ (n & 7);                 // chunk stored at position p
            f32x4 ch = *(const f32x4*)(S + row * 512 + cb * 16);
            *(f32x4*)(Kg + row * 512 + p * 16) = ch;
        }
    }

    // ======== V projection ========
    #pragma unroll
    for (int t = 0; t < 16; ++t) acc[t] = (f32x4){0.f, 0.f, 0.f, 0.f};
    {
        const bf16_t* w = wt + 65536;              // V panel wt[1][a][e]
        #pragma unroll
        for (int c = 0; c < 8; ++c)
            #pragma unroll
            for (int t = 0; t < 16; ++t) {
                bf16x8 wf = *(const bf16x8*)(w + (size_t)(t * 16 + ln) * 256 + c * 32 + lq * 8);
                acc[t] = mfma16(xf[c], wf, acc[t]);
            }
    }
    // stage transposed [a256][k16] bf16, row stride 40 B (pad spreads banks)
    #pragma unroll
    for (int t = 0; t < 16; ++t) {
        float bb = bv[t * 16 + ln];
        #pragma unroll
        for (int r = 0; r < 4; ++r)
            *(bf16_t*)(S + (t * 16 + ln) * 40 + (lq * 4 + r) * 2) = (bf16_t)(acc[t][r] + bb);
    }
    asm volatile("s_waitcnt lgkmcnt(0)" ::: "memory");
    // each lane emits one 16B k-chunk; sibling wave fills the complementary half-lines
    {
        char* Vg = Vsw + (size_t)b * 1048576 + (size_t)tile * 16384;
        const int half = lane & 1;                 // low/high 8 k of this wave's 16
        const int kq   = wid * 2 + half;           // global k-chunk 0..3
        #pragma unroll
        for (int i = 0; i < 8; ++i) {
            int a   = i * 32 + (lane >> 1);        // a-row
            int pos = kq ^ (a & 3) ^ ((a >> 2) & 3);
            f32x4 ch = *(const f32x4*)(S + a * 40 + half * 16);
            *(f32x4*)(Vg + a * 64 + pos * 16) = ch;
        }
    }
}

// ---------------- kernel 2: fused masked attention, KV-split ----------------
// Grid 512 = 32 qtiles x 2 kv-halves x 8 batches (batch = bi&7 -> XCD L2 pinning).
// Block = EXACT round-4 body (BQ=64, BK=32, 32 MFMA/wave/iter) over 32 kv tiles.
// LDS 71168 B -> 2 blocks/CU co-resident: blocks hide each other's barrier stalls
// (R6 measured 1.03 us/block-iter overlapped vs 1.67 solo).
// Raw int32 mask, depth-2 register ring: consumption never waits because each
// __syncthreads (vmcnt0 drain) has already retired loads issued >=1 body ago.
// Halves merge: atomicAdd f32 partial O into zeroed d_out; per-row partial lsum is
// parked in this block's OWN mask slot (col kvh*1024 of its own rows — a word only
// this block ever reads, and it reads it before writing). merge_kernel normalizes.
__global__ __launch_bounds__(256, 2) void flash_kernel(const float* __restrict__ x,
                                                       const float* __restrict__ WqM,
                                                       const float* __restrict__ bq,
                                                       const char* __restrict__ Ksw,
                                                       const char* __restrict__ Vsw,
                                                       int* __restrict__ mask,
                                                       float* __restrict__ out) {
    // LDS: [K0 16K][V0 16K][K1 16K][V1 16K] @0 ; Pq 2x2560 @65536 (aliases prologue
    // Pt 4x1280 — safe: last Pt read precedes the kt=0 __syncthreads) ; Ls 512 @70656.
    __shared__ __align__(16) char smem[71168];
    const int tid  = threadIdx.x;
    const int wid  = tid >> 6;
    const int lane = tid & 63;
    const int lq   = lane >> 4;
    const int ln   = lane & 15;
    const int qw   = wid >> 1;    // q half (32 rows)
    const int kw   = wid & 1;     // kv col half within tile (16 cols)
    const int batch = blockIdx.x & 7;
    const int kvh   = (blockIdx.x >> 3) & 1;     // kv half of the sequence
    const int qbase = (blockIdx.x >> 4) * 64;

    const char* Kb = Ksw + (size_t)batch * 1048576 + (size_t)(kvh * 32) * 16384;
    const char* Vb = Vsw + (size_t)batch * 1048576 + (size_t)(kvh * 32) * 16384;
    char*  Pq_ = smem + 65536 + qw * 2560;       // shared by kw pair: 32 rows x 80 B
    char*  Pt  = smem + 65536 + wid * 1280;      // wave-private (prologue only)
    float* Ls  = (float*)(smem + 70656);

    const char* kg0 = Kb + wid * 4096 + lane * 16;
    const char* vg0 = Vb + wid * 4096 + lane * 16;

    // raw mask base for this wave's rows and its kv-col strip
    int* mroot = mask + (size_t)batch * SEQ * SEQ +
                 (size_t)(qbase + qw * 32) * SEQ + kvh * 1024 + kw * 16 + ln;

    // ---- issue DMA for tile 0 (latency covered by Q prologue) ----
    {
        char* kl = smem + wid * 4096;
        char* vl = smem + 16384 + wid * 4096;
        #pragma unroll
        for (int i = 0; i < 4; ++i) gld16(kg0 + i * 1024, kl + i * 1024);
        #pragma unroll
        for (int i = 0; i < 4; ++i) gld16(vg0 + i * 1024, vl + i * 1024);
    }
    // mask ring prefill for kt = 0,1 (completes during prologue)
    int mv[2][2][4];
    #pragma unroll
    for (int w = 0; w < 2; ++w)
        #pragma unroll
        for (int h = 0; h < 2; ++h)
            #pragma unroll
            for (int r = 0; r < 4; ++r)
                mv[w][h][r] = mroot[(size_t)(h * 16 + lq * 4 + r) * SEQ + w * 32];

    // ---- Q prologue: this qw's 32 rows -> A-fragments qf[h][c] (round-4 proven) ----
    bf16x8 qf[2][8];
    {
        bf16x8 xf[2][8];
        #pragma unroll
        for (int h = 0; h < 2; ++h) {
            const float* xp = x + (size_t)(batch * SEQ + qbase + qw * 32 + h * 16 + ln) * EMB;
            #pragma unroll
            for (int c = 0; c < 8; ++c) {
                f32x4 a = *(const f32x4*)(xp + c * 32 + lq * 8);
                f32x4 b = *(const f32x4*)(xp + c * 32 + lq * 8 + 4);
                bf16x8 v;
                v[0] = (bf16_t)a[0]; v[1] = (bf16_t)a[1]; v[2] = (bf16_t)a[2]; v[3] = (bf16_t)a[3];
                v[4] = (bf16_t)b[0]; v[5] = (bf16_t)b[1]; v[6] = (bf16_t)b[2]; v[7] = (bf16_t)b[3];
                xf[h][c] = v;
            }
        }
        f32x4 qacc[2][16];
        #pragma unroll
        for (int h = 0; h < 2; ++h)
            #pragma unroll
            for (int t = 0; t < 16; ++t) qacc[h][t] = (f32x4){0.f, 0.f, 0.f, 0.f};

        char* Wsp = smem + 32768;                // buf1 as panel scratch (tile1 DMA is later)
        const int e = ln & 7;
        #pragma unroll 1
        for (int cp = 0; cp < 8; ++cp) {
            __syncthreads();
            const float* wqp = WqM + (size_t)(cp * 32) * 256 + tid;
            #pragma unroll
            for (int i = 0; i < 4; ++i) {
                bf16x8 pk;
                #pragma unroll
                for (int j = 0; j < 8; ++j)
                    pk[j] = (bf16_t)wqp[(size_t)(i * 8 + j) * 256];
                *(bf16x8*)(Wsp + tid * 128 + ((i ^ (tid & 7)) * 16)) = pk;
            }
            __syncthreads();
            #pragma unroll
            for (int t = 0; t < 16; ++t) {
                bf16x8 wf = *(const bf16x8*)(Wsp + (t * 16 + ln) * 128 + ((lq ^ e) * 16));
                qacc[0][t] = mfma16(xf[0][cp], wf, qacc[0][t]);
                qacc[1][t] = mfma16(xf[1][cp], wf, qacc[1][t]);
            }
        }
        // C-layout -> A-layout via wave-private Pt; fold bias and 1/sqrt(A)=1/16
        #pragma unroll
        for (int h = 0; h < 2; ++h) {
            #pragma unroll
            for (int c = 0; c < 8; ++c) {
                #pragma unroll
                for (int half2 = 0; half2 < 2; ++half2) {
                    int t = 2 * c + half2;
                    float bb = bq[t * 16 + ln];
                    #pragma unroll
                    for (int r = 0; r < 4; ++r) {
                        float v = (qacc[h][t][r] + bb) * 0.0625f;
                        ((bf16_t*)(Pt + (lq * 4 + r) * 80))[half2 * 16 + ln] = (bf16_t)v;
                    }
                }
                qf[h][c] = *(const bf16x8*)(Pt + ln * 80 + lq * 16);
            }
        }
    }

    // ---- main loop: 32 iterations over this block's kv half ----
    f32x4 o[2][8];
    #pragma unroll
    for (int h = 0; h < 2; ++h)
        #pragma unroll
        for (int t = 0; t < 8; ++t) o[h][t] = (f32x4){0.f, 0.f, 0.f, 0.f};
    float lsum[2][4] = {{0.f,0.f,0.f,0.f},{0.f,0.f,0.f,0.f}};

    const int kswz = ln & 7;
    const int vswz = (lq ^ (ln & 3) ^ ((ln >> 2) & 3)) * 16;
    const int n0   = kw * 16 + ln;

    for (int kt = 0; kt < 32; ++kt) {
        __syncthreads();                          // drains DMA(kt) + all prior LDS use
        if (kt + 1 < 32) {                        // prefetch tile kt+1
            int nb = (kt + 1) & 1;
            const char* kg = kg0 + (size_t)(kt + 1) * 16384;
            const char* vg = vg0 + (size_t)(kt + 1) * 16384;
            char* kl = smem + nb * 32768 + wid * 4096;
            char* vl = smem + nb * 32768 + 16384 + wid * 4096;
            #pragma unroll
            for (int i = 0; i < 4; ++i) gld16(kg + i * 1024, kl + i * 1024);
            #pragma unroll
            for (int i = 0; i < 4; ++i) gld16(vg + i * 1024, vl + i * 1024);
        }
        const int buf = kt & 1;
        const char* Ksb = smem + buf * 32768;
        const char* Vsb = smem + buf * 32768 + 16384;

        // S = Q K^T (this wave's 16 kv cols; both q subtiles share each K frag)
        f32x4 s0 = (f32x4){0.f,0.f,0.f,0.f};
        f32x4 s1 = (f32x4){0.f,0.f,0.f,0.f};
        const char* krow = Ksb + n0 * 512;
        #pragma unroll
        for (int c = 0; c < 8; ++c) {
            bf16x8 kf = *(const bf16x8*)(krow + (((c * 4 + lq) ^ kswz) * 16));
            s0 = mfma16(qf[0][c], kf, s0);
            s1 = mfma16(qf[1][c], kf, s1);
        }

        // p = mask ? exp(s) : 0 (ring slot loaded 2 barriers ago -> wait-free)
        const int (*mc)[4] = mv[kt & 1];
        #pragma unroll
        for (int r = 0; r < 4; ++r) {
            float p0 = mc[0][r] ? __expf(s0[r]) : 0.f;
            float p1 = mc[1][r] ? __expf(s1[r]) : 0.f;
            lsum[0][r] += p0;
            lsum[1][r] += p1;
            ((bf16_t*)(Pq_ + (lq * 4 + r) * 80))[kw * 16 + ln]      = (bf16_t)p0;
            ((bf16_t*)(Pq_ + (16 + lq * 4 + r) * 80))[kw * 16 + ln] = (bf16_t)p1;
        }

        // refill ring slot for kt+2 (clamped at tail; WAR on regs, no wait)
        {
            const int ktn = (kt + 2 < 32) ? kt + 2 : 31;
            int (*md)[4] = mv[kt & 1];
            #pragma unroll
            for (int h = 0; h < 2; ++h)
                #pragma unroll
                for (int r = 0; r < 4; ++r)
                    md[h][r] = mroot[(size_t)(h * 16 + lq * 4 + r) * SEQ + ktn * 32];
        }

        // P-exchange: drain LDS only — prefetch DMA stays in flight
        asm volatile("s_waitcnt lgkmcnt(0)\n\ts_barrier" ::: "memory");

        bf16x8 pa0 = *(const bf16x8*)(Pq_ + ln * 80 + lq * 16);
        bf16x8 pa1 = *(const bf16x8*)(Pq_ + (16 + ln) * 80 + lq * 16);

        // O += P V (this wave's 128 a-cols; both q subtiles share each V frag)
        const char* vbase = Vsb + (kw * 128 + ln) * 64 + vswz;
        #pragma unroll
        for (int t = 0; t < 8; ++t) {
            bf16x8 vf = *(const bf16x8*)(vbase + t * 1024);
            o[0][t] = mfma16(pa0, vf, o[0][t]);
            o[1][t] = mfma16(pa1, vf, o[1][t]);
        }
    }

    __syncthreads();
    // partial row-sum: reduce over the 16 ln lanes, publish, combine kw halves
    #pragma unroll
    for (int h = 0; h < 2; ++h) {
        #pragma unroll
        for (int r = 0; r < 4; ++r) {
            float v = lsum[h][r];
            v += __shfl_xor(v, 1);
            v += __shfl_xor(v, 2);
            v += __shfl_xor(v, 4);
            v += __shfl_xor(v, 8);
            if (ln == 0) Ls[(qw * 2 + kw) * 32 + h * 16 + lq * 4 + r] = v;
            lsum[h][r] = v;
        }
    }
    __syncthreads();

    // park this block's per-row partial lsum in its own (already fully read) mask slot
    if (kw == 0 && ln == 0) {
        #pragma unroll
        for (int h = 0; h < 2; ++h)
            #pragma unroll
            for (int r = 0; r < 4; ++r) {
                int row = h * 16 + lq * 4 + r;
                float tot = lsum[h][r] + Ls[(qw * 2 + 1) * 32 + row];
                ((float*)mask)[(size_t)batch * SEQ * SEQ +
                               (size_t)(qbase + qw * 32 + row) * SEQ + kvh * 1024] = tot;
            }
    }

    // accumulate unnormalized partial O into zeroed d_out
    #pragma unroll
    for (int h = 0; h < 2; ++h) {
        #pragma unroll
        for (int r = 0; r < 4; ++r) {
            float* orow = out + (size_t)(batch * SEQ + qbase + qw * 32 + h * 16 + lq * 4 + r) * ADIM
                          + kw * 128 + ln;
            #pragma unroll
            for (int t = 0; t < 8; ++t)
                atomicAdd(orow + t * 16, o[h][t][r]);
        }
    }
}

// ---------------- kernel 3: merge/normalize ----------------
// out[row][:] /= (l0[row] + l1[row]) with partial lsums read from the mask slots.
__global__ __launch_bounds__(256) void merge_kernel(const float* __restrict__ lbuf,
                                                    float* __restrict__ out) {
    int idx  = blockIdx.x * 256 + threadIdx.x;   // x4 elements
    int base = idx * 4;                          // 0 .. 16,777,212
    int row  = base >> 8;                        // global row 0..16383
    int b = row >> 11, r = row & 2047;
    float l0 = lbuf[(size_t)b * SEQ * SEQ + (size_t)r * SEQ];
    float l1 = lbuf[(size_t)b * SEQ * SEQ + (size_t)r * SEQ + 1024];
    float inv = 1.0f / (l0 + l1);
    f32x4 v = *(const f32x4*)(out + base);
    v[0] *= inv; v[1] *= inv; v[2] *= inv; v[3] *= inv;
    *(f32x4*)(out + base) = v;
}

// ================= launch =================
extern "C" void kernel_launch(void* const* d_in, const int* in_sizes, int n_in,
                              void* d_out, int out_size, void* d_ws, size_t ws_size,
                              hipStream_t stream) {
    const float* x    = (const float*)d_in[0];
    int*         mask = (int*)d_in[1];           // also stores per-row partial lsums
    const float* Wq   = (const float*)d_in[2];
    const float* bq   = (const float*)d_in[3];
    const float* Wk   = (const float*)d_in[4];
    const float* bk   = (const float*)d_in[5];
    const float* Wv   = (const float*)d_in[6];
    const float* bv   = (const float*)d_in[7];
    float* out = (float*)d_out;

    // ws: K_sw [0..8MB) | V_sw [8..16MB)  (pre-swizzled tile layouts) = 16 MB exactly.
    char* Ksw = (char*)d_ws;
    char* Vsw = Ksw + (size_t)8 * 1024 * 1024;
    bf16_t* wt = (bf16_t*)d_out;                 // W^T bf16 scratch, consumed by proj

    wtkv_kernel<<<512, 256, 0, stream>>>(Wk, Wv, wt);
    proj_kv<<<512, 128, 0, stream>>>(x, wt, bk, bv, Ksw, Vsw);
    // zero the f32 accumulator AFTER proj consumed wt (stream-ordered; graph-legal)
    hipMemsetAsync(d_out, 0, (size_t)out_size * sizeof(float), stream);
    flash_kernel<<<512, 256, 0, stream>>>(x, Wq, bq, Ksw, Vsw, mask, out);
    merge_kernel<<<4096, 256, 0, stream>>>((const float*)mask, out);
}